// Round 7
// baseline (310.260 us; speedup 1.0000x reference)
//
#include <hip/hip_runtime.h>

// Problem constants (from reference setup_inputs): B=2, L=10000, H=8, E=64, NE=160000
#define BB 2
#define HH 8
#define EE 64
#define ROW (HH * EE)      // 512 elements per (b, node) row
#define KVROW 2048         // bytes: 512 bf16 K elems + 512 bf16 V elems, interleaved per node
#define CH 2               // edges per LDS chunk (double-buffered)

typedef float vf4 __attribute__((ext_vector_type(4)));

// ---------- fp32 -> bf16 (RNE) ----------
__device__ inline unsigned short f2bf(float f) {
  unsigned int u = __float_as_uint(f);
  u = (u + 0x7fffu + ((u >> 16) & 1u)) >> 16;
  return (unsigned short)u;
}

// convert k,v -> INTERLEAVED bf16 kv rows: kv[b][node] = [K 1024B | V 1024B].
// threads [0, NE) also histogram dst into counts.
__global__ __launch_bounds__(256) void convert_hist_kernel(
    const float* __restrict__ k, const float* __restrict__ v,
    unsigned short* __restrict__ kv,
    const int* __restrict__ dst, int* __restrict__ counts,
    int n4, int NE) {
  int i = blockIdx.x * blockDim.x + threadIdx.x;
  if (i < n4) {
    // single-use fp32 streams: non-temporal to keep L2/L3 for the bf16 gather set
    vf4 kf = __builtin_nontemporal_load((const vf4*)k + i);
    vf4 vf = __builtin_nontemporal_load((const vf4*)v + i);
    int row = i >> 7;        // 128 float4 per 512-elem row
    int off4 = i & 127;
    // kv row = 256 ushort4 (K: 0..127, V: 128..255); kv writes are REUSED -> plain stores
    ((ushort4*)kv)[row * 256 + off4] =
        make_ushort4(f2bf(kf.x), f2bf(kf.y), f2bf(kf.z), f2bf(kf.w));
    ((ushort4*)kv)[row * 256 + 128 + off4] =
        make_ushort4(f2bf(vf.x), f2bf(vf.y), f2bf(vf.z), f2bf(vf.w));
  }
  if (i < NE) {
    atomicAdd(&counts[dst[i]], 1);
  }
}

// single-block scan: counts -> offsets[0..L]; then zero counts (reused as cursor)
__global__ __launch_bounds__(1024) void scan_kernel(
    const int* __restrict__ counts_in, int* __restrict__ counts_mut,
    int* __restrict__ offsets, int L) {
  __shared__ int sums[1024];
  int tid = threadIdx.x;
  int chunk = (L + 1023) / 1024;
  int beg = tid * chunk;
  int end = min(beg + chunk, L);
  int s = 0;
  for (int i = beg; i < end; ++i) s += counts_in[i];
  sums[tid] = s;
  __syncthreads();
  for (int off = 1; off < 1024; off <<= 1) {
    int val = 0;
    if (tid >= off) val = sums[tid - off];
    __syncthreads();
    if (tid >= off) sums[tid] += val;
    __syncthreads();
  }
  int run = (tid > 0) ? sums[tid - 1] : 0;
  for (int i = beg; i < end; ++i) {
    offsets[i] = run;
    run += counts_in[i];
    counts_mut[i] = 0;  // reuse as cursor in fill
  }
  if (tid == 1023) offsets[L] = run;
}

__global__ __launch_bounds__(256) void fill_csr_kernel(
    const int* __restrict__ dst, const int* __restrict__ src,
    const int* __restrict__ offsets, int* __restrict__ cursor,
    int* __restrict__ csr_src, int NE) {
  int e = blockIdx.x * blockDim.x + threadIdx.x;
  if (e >= NE) return;
  int d = dst[e];
  int pos = atomicAdd(&cursor[d], 1);
  csr_src[offsets[d] + pos] = src[e];
}

// ---------- fused flash-style kernel, global_load_lds edition ----------
// Rounds 1-5: compiler always sinks register-destination gathers to uses
// (VGPR pinned <=64, MLP ~2/wave) regardless of source pipelining; persistent
// TLP also no-op. Fix: direct-to-LDS DMA (no VGPR dest => cannot be sunk) +
// counted s_waitcnt vmcnt(4) so one full chunk is ALWAYS in flight per wave.
// LDS: 4 waves x 2 bufs x CH x 2KB = 32KB/block -> 5 blocks/CU.
// lane = h*8 + j covers elements 8*lane .. 8*lane+7 of the 512-elem [H,E] row.
__device__ inline void bf8_unpack(uint4 u, float* f) {
  f[0] = __uint_as_float(u.x << 16);
  f[1] = __uint_as_float(u.x & 0xffff0000u);
  f[2] = __uint_as_float(u.y << 16);
  f[3] = __uint_as_float(u.y & 0xffff0000u);
  f[4] = __uint_as_float(u.z << 16);
  f[5] = __uint_as_float(u.z & 0xffff0000u);
  f[6] = __uint_as_float(u.w << 16);
  f[7] = __uint_as_float(u.w & 0xffff0000u);
}

// Issue CH edges' K+V rows into LDS buffer BUF. Invalid (tail) edges are
// redirected to row 0 (globally hot -> L1/L2 hit, no HBM cost) so the issue
// count is ALWAYS 2*CH and the vmcnt immediate stays constant.
#define ISSUE_CHUNK(BUF, T0)                                               \
  {                                                                        \
    _Pragma("unroll") for (int i_ = 0; i_ < CH; ++i_) {                    \
      int e_ = (T0) + i_;                                                  \
      unsigned s_ = (e_ < end) ? (unsigned)csr_src[e_] : 0u;               \
      const char* row_ = kv_base + s_ * (unsigned)KVROW + lane * 16u;      \
      __builtin_amdgcn_global_load_lds(                                    \
          (const __attribute__((address_space(1))) unsigned int*)row_,     \
          (__attribute__((address_space(3))) unsigned int*)((BUF) + i_ * KVROW), \
          16, 0, 0);                                                       \
      __builtin_amdgcn_global_load_lds(                                    \
          (const __attribute__((address_space(1))) unsigned int*)(row_ + 1024), \
          (__attribute__((address_space(3))) unsigned int*)((BUF) + i_ * KVROW + 1024), \
          16, 0, 0);                                                       \
    }                                                                      \
  }

__global__ __launch_bounds__(256) void fused_attn_kernel(
    const float* __restrict__ q, const unsigned short* __restrict__ kv,
    const int* __restrict__ offsets, const int* __restrict__ csr_src,
    float* __restrict__ out, int L) {
  // [wave][buf][CH edges x 2KB]
  __shared__ __align__(16) char smem[4][2][CH * KVROW];
  const int lane = threadIdx.x & 63;
  const int warp = threadIdx.x >> 6;
  char* buf0 = &smem[warp][0][0];
  char* buf1 = &smem[warp][1][0];

  const int wslot = blockIdx.x * (blockDim.x >> 6) + warp;
  const int wstride = gridDim.x * (blockDim.x >> 6);
  const int nwid = L * BB;

  for (int wid = wslot; wid < nwid; wid += wstride) {
    int d = wid >> 1;
    int b = wid & 1;
    int beg = offsets[d];
    int end = offsets[d + 1];

    const vf4* qrow = (const vf4*)(q + ((size_t)b * L + d) * ROW);
    vf4* orow = (vf4*)(out + ((size_t)b * L + d) * ROW);

    if (beg >= end) {  // empty segment: output zeros
      vf4 z = {0.f, 0.f, 0.f, 0.f};
      __builtin_nontemporal_store(z, orow + lane * 2 + 0);
      __builtin_nontemporal_store(z, orow + lane * 2 + 1);
      continue;
    }

    const char* kv_base = (const char*)kv + (size_t)b * L * KVROW;

    // prologue: prefetch chunk 0 into buf0
    ISSUE_CHUNK(buf0, beg);

    // q row single-use: non-temporal; pre-scale by softmax_temp*log2(e) so
    // softmax runs in the exp2 domain (v_exp_f32 is natively 2^x)
    vf4 q0 = __builtin_nontemporal_load(qrow + lane * 2 + 0);
    vf4 q1 = __builtin_nontemporal_load(qrow + lane * 2 + 1);
    const float qscale = 0.125f * 1.44269504f;
    q0 *= qscale;
    q1 *= qscale;

    float m = -INFINITY;
    float l_run = 0.0f;
    float acc[8];
#pragma unroll
    for (int i = 0; i < 8; ++i) acc[i] = 0.0f;

    int nch = (end - beg + CH - 1) / CH;
    for (int c = 0; c < nch; ++c) {
      char* cur = (c & 1) ? buf1 : buf0;
      char* nxt = (c & 1) ? buf0 : buf1;
      int t0 = beg + c * CH;
      // prefetch chunk c+1 (pure-dummy past the end: row-0, L1-hot)
      ISSUE_CHUNK(nxt, t0 + CH);
      // wait for chunk c (the 2*CH youngest ops are chunk c+1's)
      asm volatile("s_waitcnt vmcnt(4)" ::: "memory");
      __builtin_amdgcn_sched_barrier(0);

      // qk phase (reads K halves from LDS)
      float qk[CH];
      float cmax = -INFINITY;
#pragma unroll
      for (int i = 0; i < CH; ++i) {
        uint4 kk = *(const uint4*)(cur + i * KVROW + lane * 16);
        float kf[8];
        bf8_unpack(kk, kf);
        float p = q0.x * kf[0] + q0.y * kf[1] + q0.z * kf[2] + q0.w * kf[3] +
                  q1.x * kf[4] + q1.y * kf[5] + q1.z * kf[6] + q1.w * kf[7];
        p += __shfl_xor(p, 1);
        p += __shfl_xor(p, 2);
        p += __shfl_xor(p, 4);
        p = (t0 + i < end) ? p : -INFINITY;  // mask tail (exact: exp2(-inf)=0)
        qk[i] = p;
        cmax = fmaxf(cmax, p);
      }
      // online-softmax rescale (defer-max: skip when scale would be 1)
      if (__any(cmax > m)) {
        float mnew = fmaxf(m, cmax);
        float scale = exp2f(m - mnew);  // first chunk: exp2(-inf)=0
        l_run *= scale;
#pragma unroll
        for (int i = 0; i < 8; ++i) acc[i] *= scale;
        m = mnew;
      }
      // accumulate phase (reads V halves from LDS)
#pragma unroll
      for (int i = 0; i < CH; ++i) {
        float a = exp2f(qk[i] - m);  // masked: exp2(-inf - m) = 0
        l_run += a;
        uint4 vv = *(const uint4*)(cur + i * KVROW + 1024 + lane * 16);
        float vf[8];
        bf8_unpack(vv, vf);
#pragma unroll
        for (int j = 0; j < 8; ++j) acc[j] += a * vf[j];
      }
    }

    float r = 1.0f / (l_run + 1e-16f);
    vf4 o0 = {acc[0] * r, acc[1] * r, acc[2] * r, acc[3] * r};
    vf4 o1 = {acc[4] * r, acc[5] * r, acc[6] * r, acc[7] * r};
    __builtin_nontemporal_store(o0, orow + lane * 2 + 0);
    __builtin_nontemporal_store(o1, orow + lane * 2 + 1);
  }
  // drain outstanding dummy prefetches before this block's LDS is reallocated
  asm volatile("s_waitcnt vmcnt(0)" ::: "memory");
}

extern "C" void kernel_launch(void* const* d_in, const int* in_sizes, int n_in,
                              void* d_out, int out_size, void* d_ws, size_t ws_size,
                              hipStream_t stream) {
  const float* q = (const float*)d_in[0];
  const float* k = (const float*)d_in[1];
  const float* v = (const float*)d_in[2];
  const int* adj = (const int*)d_in[3];

  const int NE = in_sizes[3] / 2;
  const int L = in_sizes[0] / (BB * HH * EE);
  const int* dst = adj;
  const int* src = adj + NE;
  const int nelem = BB * L * HH * EE;

  // workspace layout
  char* ws = (char*)d_ws;
  size_t off = 0;
  unsigned short* kv = (unsigned short*)(ws + off); off += (size_t)nelem * 4;  // K+V interleaved bf16
  int* counts = (int*)(ws + off);   off += (size_t)L * 4;   // doubles as cursor
  int* offsets = (int*)(ws + off);  off += (size_t)(L + 1) * 4;
  int* csr_src = (int*)(ws + off);  off += (size_t)NE * 4;

  hipMemsetAsync(counts, 0, (size_t)L * 4, stream);

  int n4 = nelem / 4;
  convert_hist_kernel<<<(n4 + 255) / 256, 256, 0, stream>>>(
      k, v, kv, dst, counts, n4, NE);

  scan_kernel<<<1, 1024, 0, stream>>>(counts, counts, offsets, L);

  fill_csr_kernel<<<(NE + 255) / 256, 256, 0, stream>>>(
      dst, src, offsets, counts, csr_src, NE);

  // persistent: 5 blocks/CU (32KB LDS each) x 256 CUs
  int nwaves = L * BB;
  int nblocks = min(1280, (nwaves + 3) / 4);
  fused_attn_kernel<<<nblocks, 256, 0, stream>>>(
      q, kv, offsets, csr_src, (float*)d_out, L);
}